// Round 2
// baseline (259.991 us; speedup 1.0000x reference)
//
#include <hip/hip_runtime.h>
#include <hip/hip_bf16.h>
#include <math.h>

typedef __attribute__((ext_vector_type(8))) short bf16x8;
typedef __attribute__((ext_vector_type(4))) float f32x4;

#define SEQ 1024
#define DIM 768
#define NH 12
#define HD 64

// ws layout (BYTE offsets):
//   Qb   bf16 [12][1024][64]  @ 0
//   Kb   bf16 [12][1024][64]  @ 1572864
//   Vt   bf16 [768][1024]     @ 3145728   (v transposed: [h*64+e][l])
//   opre bf16 [1024][768]     @ 4718592
//   G    f32  [1024][36]      @ 6291456
//   scal f32  5*[12][1024]    @ 6438912   (si, es, al, be, ga)
// u (bf16 [12][1024][64]) borrows d_out as scratch; k_oproj overwrites it last.
// NOTE (R9 post-mortem): grid.sync() costs ~50 µs on MI355X (cross-XCD barrier)
// — stream-ordered kernel boundaries are the cheap grid barrier. Never fuse
// phases with cooperative sync here.
// R10: s_i via MFMA Gram-rowsum (replaced 12-block serial cumsum). −9 µs.
// R11: kernel-count reduction (6 → 4). Evidence: per-boundary cost ~5-10 µs
// dominates (work-sum ~50 µs vs 161 measured). k_prep folded into the GEMMs
// via T14 reg-staged f32→bf16 (identical RTN cast, same swizzled LDS layout);
// RoPE table replaced by in-register rotation recurrence; k_si+k_scan2 merged
// into one per-head kernel.

__device__ __forceinline__ float wave_reduce_sum(float v) {
    for (int off = 1; off < 64; off <<= 1) v += __shfl_xor(v, off);
    return v;
}
__device__ __forceinline__ short f2bs(float x) {
    __hip_bfloat16 h = __float2bfloat16(x);
    return *reinterpret_cast<short*>(&h);
}
__device__ __forceinline__ float bs2f(short x) {
    __hip_bfloat16 h = *reinterpret_cast<__hip_bfloat16*>(&x);
    return (float)h;
}
__device__ __forceinline__ bf16x8 cvt8r(const float4& a, const float4& b) {
    bf16x8 r;
    r[0]=f2bs(a.x); r[1]=f2bs(a.y); r[2]=f2bs(a.z); r[3]=f2bs(a.w);
    r[4]=f2bs(b.x); r[5]=f2bs(b.y); r[6]=f2bs(b.z); r[7]=f2bs(b.w);
    return r;
}
__device__ __forceinline__ void async_copy16(const void* gptr, void* ldsbase, int lane) {
#if __has_builtin(__builtin_amdgcn_global_load_lds)
    __builtin_amdgcn_global_load_lds(
        (const __attribute__((address_space(1))) unsigned int*)gptr,
        (__attribute__((address_space(3))) unsigned int*)ldsbase, 16, 0, 0);
#else
    *(bf16x8*)((short*)ldsbase + lane*8) = *(const bf16x8*)gptr;
#endif
}

// ---------------- K1: 5 projections from f32 sources, 64x128 dbuf GEMM -------
// T14 reg-staging: issue float4 loads early, cvt+ds_write after the MFMAs so
// HBM/L2 latency hides under compute. A-write right after loads (only rb[] is
// held across MFMA -> ~32 extra VGPR, fits __launch_bounds__(256,3)).
// Task-packed 1D grid: exactly 400 live blocks.
// mat: 0=q 1=k 2=v(A/B swapped -> V^T row-contiguous) 3=u 4=gate.
__global__ __launch_bounds__(256, 3) void k_proj5(const float* __restrict__ Xf,
    const float* __restrict__ Wq, const float* __restrict__ Wk,
    const float* __restrict__ Wv, const float* __restrict__ Wu,
    const float* __restrict__ Wg,
    __hip_bfloat16* __restrict__ Qb, __hip_bfloat16* __restrict__ Kb,
    __hip_bfloat16* __restrict__ Vt, __hip_bfloat16* __restrict__ Ub,
    float* __restrict__ G)
{
    int t = blockIdx.x;
    int mat, rt, ct;
    if (t < 288)      { int m3 = t/96; mat = (m3==2)?3:m3; int r = t%96; rt = r/6; ct = r%6; }
    else if (t < 384) { mat = 2; int r = t-288; rt = r/8; ct = r%8; }
    else              { mat = 4; rt = t-384; ct = 0; }

    __shared__ short lds[24576];   // A dbuf @0/4096 (64x64), B dbuf @8192/16384 (128x64)

    int tid = threadIdx.x;
    int wv = tid>>6, lane = tid&63, g = lane>>4, n = lane&15;
    int wn = wv;                                       // wave owns 32 cols of 128

    const float* Asrc; const float* Bsrc; int arow0, brow0, Brows;
    if (mat == 2) { Asrc = Wv; Bsrc = Xf; arow0 = rt*64; brow0 = ct*128; Brows = SEQ; }
    else {
        Asrc = Xf; arow0 = rt*64; brow0 = ct*128;
        Bsrc = (mat==0)?Wq:(mat==1)?Wk:(mat==3)?Wu:Wg;
        Brows = (mat==4) ? 36 : DIM;
    }

    float4 ra[2][2], rb[4][2];
    auto load_step = [&](int k0) {
#pragma unroll
        for (int p = 0; p < 2; ++p) {                  // A: 64 rows x 8 chunks
            int s = p*256 + wv*64 + lane;
            int r = s >> 3, c = s & 7, cl = c ^ (r & 7);
            const float* sp = Asrc + (size_t)(arow0 + r)*DIM + k0 + cl*8;
            ra[p][0] = *(const float4*)sp; ra[p][1] = *(const float4*)(sp + 4);
        }
#pragma unroll
        for (int p = 0; p < 4; ++p) {                  // B: 128 rows x 8 chunks
            int s = p*256 + wv*64 + lane;
            int r = s >> 3, c = s & 7, cl = c ^ (r & 7);
            int gr = brow0 + r; if (gr >= Brows) gr = Brows - 1;   // gate clamp
            const float* sp = Bsrc + (size_t)gr*DIM + k0 + cl*8;
            rb[p][0] = *(const float4*)sp; rb[p][1] = *(const float4*)(sp + 4);
        }
    };
    auto writeA = [&](int buf) {
        short* Ab = lds + buf*4096;
#pragma unroll
        for (int p = 0; p < 2; ++p) {
            int s = p*256 + wv*64 + lane;
            *(bf16x8*)(Ab + s*8) = cvt8r(ra[p][0], ra[p][1]);
        }
    };
    auto writeB = [&](int buf) {
        short* Bb = lds + 8192 + buf*8192;
#pragma unroll
        for (int p = 0; p < 4; ++p) {
            int s = p*256 + wv*64 + lane;
            *(bf16x8*)(Bb + s*8) = cvt8r(rb[p][0], rb[p][1]);
        }
    };

    f32x4 acc[4][2];
    for (int i=0;i<4;++i) for (int j=0;j<2;++j) acc[i][j] = (f32x4){0,0,0,0};

    load_step(0); writeA(0); writeB(0);
    for (int it = 0; it < 12; ++it) {
        __syncthreads();                      // buf it&1 fully written
        if (it < 11) { load_step((it + 1)*64); writeA(1 - (it & 1)); }
        int buf = it & 1;
        const short* Ab = lds + buf*4096;
        const short* Bb = lds + 8192 + buf*8192;
        for (int ks = 0; ks < 2; ++ks) {
            int q = ks*4 + g;
            bf16x8 af[4], bfr[2];
            for (int i=0;i<4;++i)
                af[i] = *(const bf16x8*)(&Ab[((i*16+n)*8 + (q ^ (n&7)))*8]);
            for (int j=0;j<2;++j)
                bfr[j] = *(const bf16x8*)(&Bb[((wn*32+j*16+n)*8 + (q ^ (n&7)))*8]);
            for (int i=0;i<4;++i)
                for (int j=0;j<2;++j)
                    acc[i][j] = __builtin_amdgcn_mfma_f32_16x16x32_bf16(af[i], bfr[j], acc[i][j], 0,0,0);
        }
        if (it < 11) writeB(1 - (it & 1));    // cvt+write after MFMA (T14)
    }
    __syncthreads();

    // ---- gate: tiny, direct f32 writes ----
    if (mat == 4) {
        for (int i=0;i<4;++i) for (int j=0;j<2;++j) for (int r=0;r<4;++r) {
            int row = rt*64 + i*16 + g*4 + r;
            int col = wn*32 + j*16 + n;
            if (col < 36) G[(size_t)row*36 + col] = acc[i][j][r];
        }
        return;
    }

    // ---- stage C tile bf16 [64 rows][128 cols] in LDS (reuses A buffers) ----
    short* C = lds;
    for (int i=0;i<4;++i) for (int j=0;j<2;++j) for (int r=0;r<4;++r)
        C[(i*16 + g*4 + r)*128 + wn*32 + j*16 + n] = f2bs(acc[i][j][r]);
    __syncthreads();

    if (mat == 2) {
        // C[e_local][l_local] -> Vt[e][l], 256B runs via uint
        for (int k = 0; k < 16; ++k) {
            int row = k*4 + wv;
            unsigned int v = ((const unsigned int*)C)[row*64 + lane];
            ((unsigned int*)(Vt + (size_t)(rt*64 + row)*SEQ + ct*128))[lane] = v;
        }
    } else if (mat == 3) {
        for (int k = 0; k < 32; ++k) {
            int u = k*4 + wv;             // 0..127 row-head pairs
            int row = u >> 1, hsel = u & 1;
            Ub[((size_t)(2*ct + hsel)*SEQ + rt*64 + row)*HD + lane] =
                *(__hip_bfloat16*)&C[row*128 + hsel*64 + lane];
        }
    } else {
        // q/k: fused RoPE (rotation recurrence) + L2 normalize, head-major write
        // lane's rows are l = rt*64 + 2k + b (arith. progression, step 2) ->
        // angle advances by 2*inv per k: rotate (c0,s0) by (C2,S2). 2 sincosf
        // per lane total; drift ~32 ulp << bf16 quantization.
        __hip_bfloat16* dst = (mat==0) ? Qb : Kb;
        int i2 = lane >> 1;
        int b = wv >> 1, hsel = wv & 1;
        float inv = expf((float)i2 * (-9.210340371976184f / 32.f));  // 10000^{-i2/32}
        float c0, s0, C2, S2;
        sincosf((float)(rt*64 + b) * inv, &s0, &c0);
        sincosf(2.f * inv, &S2, &C2);
        for (int k = 0; k < 32; ++k) {
            int row = 2*k + b;
            int l = rt*64 + row;
            float x = bs2f(C[row*128 + hsel*64 + lane]);
            float p = __shfl(x, lane ^ 32);
            float rot = (lane < 32) ? -p : p;
            float y = x*c0 + rot*s0;
            float nrm = wave_reduce_sum(y*y);
            y = y / fmaxf(sqrtf(nrm), 1e-12f);
            dst[((size_t)(2*ct + hsel)*SEQ + l)*HD + lane] = __float2bfloat16(y);
            float cn = c0*C2 - s0*S2;
            s0 = s0*C2 + c0*S2;
            c0 = cn;
        }
    }
}

// ---------------- K2: per-head s_i (MFMA Gram rowsum) + E/P scans ------------
// One block per head, 1024 threads. Phase A: 16 waves x 4 row-tiles of 16,
// K-split dual accumulators (halves the MFMA dependency chain). Phase B:
// wave 0 runs smax + prefix scans from LDS (old k_scan2).
__global__ __launch_bounds__(1024) void k_sscan(const __hip_bfloat16* __restrict__ Ub,
    const float* __restrict__ Gm, const float* __restrict__ pmu,
    const float* __restrict__ plt,
    float* __restrict__ si_, float* __restrict__ es_, float* __restrict__ al_,
    float* __restrict__ be_, float* __restrict__ ga_)
{
    int h = blockIdx.x;
    int tid = threadIdx.x, wv = tid >> 6, lane = tid & 63, g = lane >> 4, n = lane & 15;
    __shared__ float sbuf[SEQ];
    const short* ub = (const short*)Ub + (size_t)h*SEQ*HD;
    float ltv = fminf(fmaxf(plt[h], -50.f), 30.f);
    float ltau = expf(ltv);

    for (int tt = 0; tt < 4; ++tt) {
        int rt16 = tt*16 + wv;             // row-tile 0..63 (16 rows each)
        int lbase = rt16*16;
        bf16x8 a0 = *(const bf16x8*)(ub + (size_t)(lbase + n)*HD + g*8);
        bf16x8 a1 = *(const bf16x8*)(ub + (size_t)(lbase + n)*HD + 32 + g*8);
        f32x4 accA = (f32x4){0,0,0,0}, accB = (f32x4){0,0,0,0};
        for (int jt = 0; jt < rt16; ++jt) {            // strictly-below: unmasked
            const short* br = ub + (size_t)(jt*16 + n)*HD + g*8;
            bf16x8 b0 = *(const bf16x8*)br;
            bf16x8 b1 = *(const bf16x8*)(br + 32);
            accA = __builtin_amdgcn_mfma_f32_16x16x32_bf16(a0, b0, accA, 0,0,0);
            accB = __builtin_amdgcn_mfma_f32_16x16x32_bf16(a1, b1, accB, 0,0,0);
        }
        float p[4];
        for (int r = 0; r < 4; ++r) {                  // prior-mu term (partial cols)
            int l = lbase + g*4 + r;
            float acc = 0.f;
            for (int c = n; c < 64; c += 16)
                acc += bs2f(ub[(size_t)l*HD + c]) * pmu[h*HD + c];
            p[r] = ltau*acc + accA[r] + accB[r];
        }
        {                                              // diagonal tile: mask j<=l
            const short* br = ub + (size_t)(lbase + n)*HD + g*8;
            bf16x8 b0 = *(const bf16x8*)br;
            bf16x8 b1 = *(const bf16x8*)(br + 32);
            f32x4 d = (f32x4){0,0,0,0};
            d = __builtin_amdgcn_mfma_f32_16x16x32_bf16(a0, b0, d, 0,0,0);
            d = __builtin_amdgcn_mfma_f32_16x16x32_bf16(a1, b1, d, 0,0,0);
            for (int r = 0; r < 4; ++r) if (n <= g*4 + r) p[r] += d[r];
        }
        for (int off = 1; off < 16; off <<= 1)         // rowsum over 16 j-cols
            for (int r = 0; r < 4; ++r) p[r] += __shfl_xor(p[r], off);
        if (n == 0) {
            for (int r = 0; r < 4; ++r) {
                int l = lbase + g*4 + r;
                float v = -p[r] * 0.125f / (ltau + (float)(l + 1));
                sbuf[l] = v;
                si_[h*SEQ + l] = v;
            }
        }
    }
    __syncthreads();
    if (wv != 0) return;
    // ---- phase B: wave 0, smax + E/P scans -> es/alpha/beta/gamma ----
    int base = lane * 16;
    float sv[16], ev[16];
    float vm = -1e30f;
#pragma unroll
    for (int i = 0; i < 16; ++i) { sv[i] = sbuf[base + i]; vm = fmaxf(vm, sv[i]); }
    for (int off = 1; off < 64; off <<= 1) vm = fmaxf(vm, __shfl_xor(vm, off));
    float se = 0.f, ss = 0.f;
#pragma unroll
    for (int i = 0; i < 16; ++i) {
        ev[i] = expf(fminf(sv[i] - vm, 0.f));
        se += ev[i]; ss += sv[i];
    }
    float pe = se, ps = ss;
    for (int off = 1; off < 64; off <<= 1) {
        float t1 = __shfl_up(pe, off), t2 = __shfl_up(ps, off);
        if (lane >= off) { pe += t1; ps += t2; }
    }
    float E = pe - se, P = ps - ss;         // exclusive prefixes
#pragma unroll
    for (int i = 0; i < 16; ++i) {
        int l = base + i;
        E += ev[i]; P += sv[i];
        float t = (float)(l + 1);
        float s1 = 1.f / (1.f + expf(-Gm[(size_t)l*36 + h*3 + 0]));
        float sh = 1.f / (1.f + expf(-Gm[(size_t)l*36 + h*3 + 1]));
        float a = sh / (E + 1e-12f);
        float b = (s1 - sh) / t;
        float gm = -((b * P + sh) / t);
        es_[h*SEQ + l] = ev[i];
        al_[h*SEQ + l] = a;
        be_[h*SEQ + l] = b;
        ga_[h*SEQ + l] = gm;
    }
}

// ---------------- K4: causal weighted linear attention + LayerNorm -------------
__global__ __launch_bounds__(256) void k_attn(const __hip_bfloat16* __restrict__ Qb,
    const __hip_bfloat16* __restrict__ Kb, const __hip_bfloat16* __restrict__ Vt,
    const float* __restrict__ si_, const float* __restrict__ es_,
    const float* __restrict__ al_, const float* __restrict__ be_,
    const float* __restrict__ ga_, __hip_bfloat16* __restrict__ opre)
{
    int t = blockIdx.x, h = blockIdx.y;   // q-tile 0..63
    int wv = threadIdx.x >> 6, lane = threadIdx.x & 63;
    int g = lane >> 4, n = lane & 15;
    __shared__ short P[4][16*64];
    __shared__ float Op[4][16][64];
    short* Pw = P[wv];
    int m0 = t*16;
    const short* qrow = (const short*)Qb + ((size_t)h*SEQ + m0 + n)*HD + g*8;
    bf16x8 qa0 = *(const bf16x8*)qrow;
    bf16x8 qa1 = *(const bf16x8*)(qrow + 32);
    const float* al = al_ + h*SEQ;
    const float* be = be_ + h*SEQ;
    const float* ga = ga_ + h*SEQ;
    const float* es = es_ + h*SEQ;
    const float* si = si_ + h*SEQ;
    float A_[4], B_[4], G_[4];
    for (int r = 0; r < 4; ++r) {
        int m = m0 + g*4 + r;
        A_[r] = al[m]; B_[r] = be[m]; G_[r] = ga[m];
    }
    f32x4 acco[4];
    for (int et = 0; et < 4; ++et) acco[et] = (f32x4){0.f,0.f,0.f,0.f};

    int jtmax = t >> 2;
    for (int jt = wv; jt <= jtmax; jt += 4) {
        int j0 = jt*64;
        for (int ct = 0; ct < 4; ++ct) {
            const short* krow = (const short*)Kb + ((size_t)h*SEQ + j0 + ct*16 + n)*HD + g*8;
            bf16x8 kb0 = *(const bf16x8*)krow;
            bf16x8 kb1 = *(const bf16x8*)(krow + 32);
            f32x4 sacc = {0.f,0.f,0.f,0.f};
            sacc = __builtin_amdgcn_mfma_f32_16x16x32_bf16(qa0, kb0, sacc, 0, 0, 0);
            sacc = __builtin_amdgcn_mfma_f32_16x16x32_bf16(qa1, kb1, sacc, 0, 0, 0);
            int j = j0 + ct*16 + n;
            float ej = es[j], sj = si[j];
            int chunk = ct*2 + (n>>3), e = n&7;
            for (int r = 0; r < 4; ++r) {
                int m = m0 + g*4 + r;
                float w = (j <= m) ? (A_[r]*ej + B_[r]*sj + G_[r]) : 0.f;
                int ml = g*4 + r;
                Pw[ml*64 + (chunk ^ (ml&7))*8 + e] = f2bs(w * sacc[r]);
            }
        }
        const short* vb = (const short*)Vt + (size_t)h*HD*SEQ;
        for (int et = 0; et < 4; ++et) {
            for (int sub = 0; sub < 2; ++sub) {
                int q = sub*4 + g;
                bf16x8 pa = *(const bf16x8*)(&Pw[n*64 + (q ^ (n&7))*8]);
                bf16x8 vfr = *(const bf16x8*)(vb + (size_t)(et*16 + n)*SEQ + j0 + sub*32 + g*8);
                acco[et] = __builtin_amdgcn_mfma_f32_16x16x32_bf16(pa, vfr, acco[et], 0, 0, 0);
            }
        }
    }
    for (int et = 0; et < 4; ++et)
        for (int r = 0; r < 4; ++r)
            Op[wv][g*4 + r][et*16 + n] = acco[et][r];
    __syncthreads();
    for (int rr = 0; rr < 4; ++rr) {
        int row = wv*4 + rr;
        float v = Op[0][row][lane] + Op[1][row][lane] + Op[2][row][lane] + Op[3][row][lane];
        float sm = wave_reduce_sum(v);
        float sq = wave_reduce_sum(v*v);
        float mu = sm * (1.f/64.f);
        float var = fmaxf(sq * (1.f/64.f) - mu*mu, 0.f);
        float invs = rsqrtf(var + 1e-5f);
        opre[(size_t)(m0 + row)*DIM + h*HD + lane] = __float2bfloat16((v - mu) * invs);
    }
}

// ---------------- K5: output projection, A via DMA, B reg-staged from f32 Wo -
__global__ __launch_bounds__(256, 4) void k_oproj(const short* __restrict__ A,
    const float* __restrict__ Wo, float* __restrict__ out)
{
    int rt = blockIdx.x, ct = blockIdx.y;
    __shared__ short lds[16384];   // A dbuf @0/4096, B dbuf @8192/12288 (64x64)

    int tid = threadIdx.x;
    int wv = tid>>6, lane = tid&63, g = lane>>4, n = lane&15;
    int wm = wv>>1, wn = wv&1;

    float4 rb[2][2];
    auto dmaA = [&](int buf, int k0) {
        short* Ab = lds + buf*4096;
#pragma unroll
        for (int p = 0; p < 2; ++p) {
            int sbase = p*256 + wv*64;
            int s = sbase + lane;
            int r = s >> 3, c = s & 7, cl = c ^ (r & 7);
            async_copy16(A + (size_t)(rt*64 + r)*DIM + k0 + cl*8, Ab + sbase*8, lane);
        }
    };
    auto loadB = [&](int k0) {
#pragma unroll
        for (int p = 0; p < 2; ++p) {
            int s = p*256 + wv*64 + lane;
            int r = s >> 3, c = s & 7, cl = c ^ (r & 7);
            const float* sp = Wo + (size_t)(ct*64 + r)*DIM + k0 + cl*8;
            rb[p][0] = *(const float4*)sp; rb[p][1] = *(const float4*)(sp + 4);
        }
    };
    auto writeB = [&](int buf) {
        short* Bb = lds + 8192 + buf*4096;
#pragma unroll
        for (int p = 0; p < 2; ++p) {
            int s = p*256 + wv*64 + lane;
            *(bf16x8*)(Bb + s*8) = cvt8r(rb[p][0], rb[p][1]);
        }
    };

    f32x4 acc[2][2];
    for (int i=0;i<2;++i) for (int j=0;j<2;++j) acc[i][j] = (f32x4){0,0,0,0};

    dmaA(0, 0); loadB(0); writeB(0);
    for (int it = 0; it < 12; ++it) {
        __syncthreads();                      // drains A-DMA + orders B writes
        if (it < 11) { dmaA(1 - (it & 1), (it + 1)*64); loadB((it + 1)*64); }
        int buf = it & 1;
        const short* Ab = lds + buf*4096;
        const short* Bb = lds + 8192 + buf*4096;
        for (int ks = 0; ks < 2; ++ks) {
            int q = ks*4 + g;
            bf16x8 af[2], bfr[2];
            for (int i=0;i<2;++i)
                af[i] = *(const bf16x8*)(&Ab[((wm*32+i*16+n)*8 + (q ^ (n&7)))*8]);
            for (int j=0;j<2;++j)
                bfr[j] = *(const bf16x8*)(&Bb[((wn*32+j*16+n)*8 + (q ^ (n&7)))*8]);
            for (int i=0;i<2;++i)
                for (int j=0;j<2;++j)
                    acc[i][j] = __builtin_amdgcn_mfma_f32_16x16x32_bf16(af[i], bfr[j], acc[i][j], 0,0,0);
        }
        if (it < 11) writeB(1 - (it & 1));    // cvt+write after MFMA (T14)
    }
    for (int i=0;i<2;++i) for (int j=0;j<2;++j) for (int r=0;r<4;++r) {
        int row = rt*64 + wm*32 + i*16 + g*4 + r;
        int col = ct*64 + wn*32 + j*16 + n;
        out[(size_t)row*DIM + col] = acc[i][j][r];
    }
}

extern "C" void kernel_launch(void* const* d_in, const int* in_sizes, int n_in,
                              void* d_out, int out_size, void* d_ws, size_t ws_size,
                              hipStream_t stream) {
    const float* X   = (const float*)d_in[0];
    const float* Wq  = (const float*)d_in[1];
    const float* Wk  = (const float*)d_in[2];
    const float* Wv  = (const float*)d_in[3];
    const float* Wu  = (const float*)d_in[4];
    const float* Wg  = (const float*)d_in[5];
    const float* Wo  = (const float*)d_in[6];
    const float* pmu = (const float*)d_in[7];
    const float* plt = (const float*)d_in[8];

    char* w = (char*)d_ws;
    __hip_bfloat16* Qb   = (__hip_bfloat16*)(w + 0);
    __hip_bfloat16* Kb   = (__hip_bfloat16*)(w + 1572864);
    __hip_bfloat16* Vt   = (__hip_bfloat16*)(w + 3145728);
    __hip_bfloat16* opre = (__hip_bfloat16*)(w + 4718592);
    float*          G    = (float*)(w + 6291456);
    float*          si_  = (float*)(w + 6438912);
    float*          es_  = si_ + NH*SEQ;
    float*          al_  = es_ + NH*SEQ;
    float*          be_  = al_ + NH*SEQ;
    float*          ga_  = be_ + NH*SEQ;
    __hip_bfloat16* Ub   = (__hip_bfloat16*)d_out;   // scratch; k_oproj overwrites last
    float*          out  = (float*)d_out;

    hipLaunchKernelGGL(k_proj5, dim3(400), dim3(256), 0, stream,
                       X, Wq, Wk, Wv, Wu, Wg, Qb, Kb, Vt, Ub, G);
    hipLaunchKernelGGL(k_sscan, dim3(NH), dim3(1024), 0, stream,
                       Ub, G, pmu, plt, si_, es_, al_, be_, ga_);
    hipLaunchKernelGGL(k_attn, dim3(64, NH), dim3(256), 0, stream,
                       Qb, Kb, Vt, si_, es_, al_, be_, ga_, opre);
    hipLaunchKernelGGL(k_oproj, dim3(16, 12), dim3(256), 0, stream,
                       (const short*)opre, Wo, out);
}

// Round 3
// 164.182 us; speedup vs baseline: 1.5835x; 1.5835x over previous
//
#include <hip/hip_runtime.h>
#include <hip/hip_bf16.h>
#include <math.h>

typedef __attribute__((ext_vector_type(8))) short bf16x8;
typedef __attribute__((ext_vector_type(4))) float f32x4;

#define SEQ 1024
#define DIM 768
#define NH 12
#define HD 64

// ws layout (BYTE offsets):
//   Qb   bf16 [12][1024][64]  @ 0
//   Kb   bf16 [12][1024][64]  @ 1572864
//   Vt   bf16 [768][1024]     @ 3145728   (v transposed: [h*64+e][l])
//   opre bf16 [1024][768]     @ 4718592
//   G    f32  [1024][36]      @ 6291456
//   scal f32  5*[12][1024]    @ 6438912   (si, es, al, be, ga)
// u (bf16 [12][1024][64]) borrows d_out as scratch; k_oproj overwrites it last.
// NOTE (R9 post-mortem): grid.sync() costs ~50 µs on MI355X (cross-XCD barrier)
// — stream-ordered kernel boundaries are the cheap grid barrier. Never fuse
// phases with cooperative sync here.
// R10: s_i via MFMA Gram-rowsum (replaced 12-block serial cumsum). −9 µs.
// R11: k_prep folded into GEMMs via T14 reg-staged f32→bf16 (good: ~−18 µs on
// those phases); k_si+k_scan2 merged into one 1024-thread kernel (BAD).
// R12 post-mortem: merged k_sscan got VGPR_Count=32 (compiler occupancy
// heuristic for 1024-thr blocks) -> sv[16]/ev[16]+MFMA state spilled to
// scratch -> 125 µs of idle-stall on 12 blocks. NEVER put reg-array phases and
// MFMA phases in one max-size workgroup. Reverted to split k_si (192 blocks)
// + k_scan2; a launch boundary (~7 µs) is far cheaper than a spill.

__device__ __forceinline__ float wave_reduce_sum(float v) {
    for (int off = 1; off < 64; off <<= 1) v += __shfl_xor(v, off);
    return v;
}
__device__ __forceinline__ short f2bs(float x) {
    __hip_bfloat16 h = __float2bfloat16(x);
    return *reinterpret_cast<short*>(&h);
}
__device__ __forceinline__ float bs2f(short x) {
    __hip_bfloat16 h = *reinterpret_cast<__hip_bfloat16*>(&x);
    return (float)h;
}
__device__ __forceinline__ bf16x8 cvt8r(const float4& a, const float4& b) {
    bf16x8 r;
    r[0]=f2bs(a.x); r[1]=f2bs(a.y); r[2]=f2bs(a.z); r[3]=f2bs(a.w);
    r[4]=f2bs(b.x); r[5]=f2bs(b.y); r[6]=f2bs(b.z); r[7]=f2bs(b.w);
    return r;
}
__device__ __forceinline__ void async_copy16(const void* gptr, void* ldsbase, int lane) {
#if __has_builtin(__builtin_amdgcn_global_load_lds)
    __builtin_amdgcn_global_load_lds(
        (const __attribute__((address_space(1))) unsigned int*)gptr,
        (__attribute__((address_space(3))) unsigned int*)ldsbase, 16, 0, 0);
#else
    *(bf16x8*)((short*)ldsbase + lane*8) = *(const bf16x8*)gptr;
#endif
}

// ---------------- K1: 5 projections from f32 sources, 64x128 dbuf GEMM -------
// T14 reg-staging: issue float4 loads early, cvt+ds_write after the MFMAs so
// HBM/L2 latency hides under compute.
// Task-packed 1D grid: exactly 400 live blocks.
// mat: 0=q 1=k 2=v(A/B swapped -> V^T row-contiguous) 3=u 4=gate.
__global__ __launch_bounds__(256, 3) void k_proj5(const float* __restrict__ Xf,
    const float* __restrict__ Wq, const float* __restrict__ Wk,
    const float* __restrict__ Wv, const float* __restrict__ Wu,
    const float* __restrict__ Wg,
    __hip_bfloat16* __restrict__ Qb, __hip_bfloat16* __restrict__ Kb,
    __hip_bfloat16* __restrict__ Vt, __hip_bfloat16* __restrict__ Ub,
    float* __restrict__ G)
{
    int t = blockIdx.x;
    int mat, rt, ct;
    if (t < 288)      { int m3 = t/96; mat = (m3==2)?3:m3; int r = t%96; rt = r/6; ct = r%6; }
    else if (t < 384) { mat = 2; int r = t-288; rt = r/8; ct = r%8; }
    else              { mat = 4; rt = t-384; ct = 0; }

    __shared__ short lds[24576];   // A dbuf @0/4096 (64x64), B dbuf @8192/16384 (128x64)

    int tid = threadIdx.x;
    int wv = tid>>6, lane = tid&63, g = lane>>4, n = lane&15;
    int wn = wv;                                       // wave owns 32 cols of 128

    const float* Asrc; const float* Bsrc; int arow0, brow0, Brows;
    if (mat == 2) { Asrc = Wv; Bsrc = Xf; arow0 = rt*64; brow0 = ct*128; Brows = SEQ; }
    else {
        Asrc = Xf; arow0 = rt*64; brow0 = ct*128;
        Bsrc = (mat==0)?Wq:(mat==1)?Wk:(mat==3)?Wu:Wg;
        Brows = (mat==4) ? 36 : DIM;
    }

    float4 ra[2][2], rb[4][2];
    auto load_step = [&](int k0) {
#pragma unroll
        for (int p = 0; p < 2; ++p) {                  // A: 64 rows x 8 chunks
            int s = p*256 + wv*64 + lane;
            int r = s >> 3, c = s & 7, cl = c ^ (r & 7);
            const float* sp = Asrc + (size_t)(arow0 + r)*DIM + k0 + cl*8;
            ra[p][0] = *(const float4*)sp; ra[p][1] = *(const float4*)(sp + 4);
        }
#pragma unroll
        for (int p = 0; p < 4; ++p) {                  // B: 128 rows x 8 chunks
            int s = p*256 + wv*64 + lane;
            int r = s >> 3, c = s & 7, cl = c ^ (r & 7);
            int gr = brow0 + r; if (gr >= Brows) gr = Brows - 1;   // gate clamp
            const float* sp = Bsrc + (size_t)gr*DIM + k0 + cl*8;
            rb[p][0] = *(const float4*)sp; rb[p][1] = *(const float4*)(sp + 4);
        }
    };
    auto writeA = [&](int buf) {
        short* Ab = lds + buf*4096;
#pragma unroll
        for (int p = 0; p < 2; ++p) {
            int s = p*256 + wv*64 + lane;
            *(bf16x8*)(Ab + s*8) = cvt8r(ra[p][0], ra[p][1]);
        }
    };
    auto writeB = [&](int buf) {
        short* Bb = lds + 8192 + buf*8192;
#pragma unroll
        for (int p = 0; p < 4; ++p) {
            int s = p*256 + wv*64 + lane;
            *(bf16x8*)(Bb + s*8) = cvt8r(rb[p][0], rb[p][1]);
        }
    };

    f32x4 acc[4][2];
    for (int i=0;i<4;++i) for (int j=0;j<2;++j) acc[i][j] = (f32x4){0,0,0,0};

    load_step(0); writeA(0); writeB(0);
    for (int it = 0; it < 12; ++it) {
        __syncthreads();                      // buf it&1 fully written
        if (it < 11) { load_step((it + 1)*64); writeA(1 - (it & 1)); }
        int buf = it & 1;
        const short* Ab = lds + buf*4096;
        const short* Bb = lds + 8192 + buf*8192;
        for (int ks = 0; ks < 2; ++ks) {
            int q = ks*4 + g;
            bf16x8 af[4], bfr[2];
            for (int i=0;i<4;++i)
                af[i] = *(const bf16x8*)(&Ab[((i*16+n)*8 + (q ^ (n&7)))*8]);
            for (int j=0;j<2;++j)
                bfr[j] = *(const bf16x8*)(&Bb[((wn*32+j*16+n)*8 + (q ^ (n&7)))*8]);
            for (int i=0;i<4;++i)
                for (int j=0;j<2;++j)
                    acc[i][j] = __builtin_amdgcn_mfma_f32_16x16x32_bf16(af[i], bfr[j], acc[i][j], 0,0,0);
        }
        if (it < 11) writeB(1 - (it & 1));    // cvt+write after MFMA (T14)
    }
    __syncthreads();

    // ---- gate: tiny, direct f32 writes ----
    if (mat == 4) {
        for (int i=0;i<4;++i) for (int j=0;j<2;++j) for (int r=0;r<4;++r) {
            int row = rt*64 + i*16 + g*4 + r;
            int col = wn*32 + j*16 + n;
            if (col < 36) G[(size_t)row*36 + col] = acc[i][j][r];
        }
        return;
    }

    // ---- stage C tile bf16 [64 rows][128 cols] in LDS (reuses A buffers) ----
    short* C = lds;
    for (int i=0;i<4;++i) for (int j=0;j<2;++j) for (int r=0;r<4;++r)
        C[(i*16 + g*4 + r)*128 + wn*32 + j*16 + n] = f2bs(acc[i][j][r]);
    __syncthreads();

    if (mat == 2) {
        // C[e_local][l_local] -> Vt[e][l], 256B runs via uint
        for (int k = 0; k < 16; ++k) {
            int row = k*4 + wv;
            unsigned int v = ((const unsigned int*)C)[row*64 + lane];
            ((unsigned int*)(Vt + (size_t)(rt*64 + row)*SEQ + ct*128))[lane] = v;
        }
    } else if (mat == 3) {
        for (int k = 0; k < 32; ++k) {
            int u = k*4 + wv;             // 0..127 row-head pairs
            int row = u >> 1, hsel = u & 1;
            Ub[((size_t)(2*ct + hsel)*SEQ + rt*64 + row)*HD + lane] =
                *(__hip_bfloat16*)&C[row*128 + hsel*64 + lane];
        }
    } else {
        // q/k: fused RoPE (rotation recurrence) + L2 normalize, head-major write
        __hip_bfloat16* dst = (mat==0) ? Qb : Kb;
        int i2 = lane >> 1;
        int b = wv >> 1, hsel = wv & 1;
        float inv = expf((float)i2 * (-9.210340371976184f / 32.f));  // 10000^{-i2/32}
        float c0, s0, C2, S2;
        sincosf((float)(rt*64 + b) * inv, &s0, &c0);
        sincosf(2.f * inv, &S2, &C2);
        for (int k = 0; k < 32; ++k) {
            int row = 2*k + b;
            int l = rt*64 + row;
            float x = bs2f(C[row*128 + hsel*64 + lane]);
            float p = __shfl(x, lane ^ 32);
            float rot = (lane < 32) ? -p : p;
            float y = x*c0 + rot*s0;
            float nrm = wave_reduce_sum(y*y);
            y = y / fmaxf(sqrtf(nrm), 1e-12f);
            dst[((size_t)(2*ct + hsel)*SEQ + l)*HD + lane] = __float2bfloat16(y);
            float cn = c0*C2 - s0*S2;
            s0 = s0*C2 + c0*S2;
            c0 = cn;
        }
    }
}

// ---------------- K2a: s_i via MFMA causal Gram rowsum (R1-verbatim) ---------
// s_i[l] = -(ltau*(u[l].mu) + sum_{j<=l} u[l].u[j]) / (8*(ltau+l+1))
// Block (T,h): rows l in [64T, 64T+64); wave wv owns 16 rows, loops j-tiles.
__global__ __launch_bounds__(256) void k_si(const __hip_bfloat16* __restrict__ Ub,
    const float* __restrict__ pmu, const float* __restrict__ plt,
    float* __restrict__ si_)
{
    int T = blockIdx.x, h = blockIdx.y;
    int wv = threadIdx.x >> 6, lane = threadIdx.x & 63;
    int g = lane >> 4, n = lane & 15;
    int lbase = T*64 + wv*16;
    const short* ub = (const short*)Ub + (size_t)h*SEQ*HD;

    bf16x8 a0 = *(const bf16x8*)(ub + (size_t)(lbase + n)*HD + g*8);
    bf16x8 a1 = *(const bf16x8*)(ub + (size_t)(lbase + n)*HD + 32 + g*8);

    float ltv = fminf(fmaxf(plt[h], -50.f), 30.f);
    float ltau = expf(ltv);

    float p[4];
    for (int r = 0; r < 4; ++r) {          // prior-mu term, partial over cols {n,16+n,32+n,48+n}
        int l = lbase + g*4 + r;
        float acc = 0.f;
        for (int c = n; c < 64; c += 16)
            acc += bs2f(ub[(size_t)l*HD + c]) * pmu[h*HD + c];
        p[r] = ltau * acc;
    }

    int diag = 4*T + wv;                   // diagonal 16-tile index
    for (int jt = 0; jt < diag; ++jt) {    // strictly-below tiles: unmasked
        const short* br = ub + (size_t)(jt*16 + n)*HD + g*8;
        bf16x8 b0 = *(const bf16x8*)br;
        bf16x8 b1 = *(const bf16x8*)(br + 32);
        f32x4 sacc = {0.f,0.f,0.f,0.f};
        sacc = __builtin_amdgcn_mfma_f32_16x16x32_bf16(a0, b0, sacc, 0,0,0);
        sacc = __builtin_amdgcn_mfma_f32_16x16x32_bf16(a1, b1, sacc, 0,0,0);
        for (int r = 0; r < 4; ++r) p[r] += sacc[r];
    }
    {                                      // diagonal tile: mask j<=l  (n <= g*4+r)
        const short* br = ub + (size_t)(diag*16 + n)*HD + g*8;
        bf16x8 b0 = *(const bf16x8*)br;
        bf16x8 b1 = *(const bf16x8*)(br + 32);
        f32x4 sacc = {0.f,0.f,0.f,0.f};
        sacc = __builtin_amdgcn_mfma_f32_16x16x32_bf16(a0, b0, sacc, 0,0,0);
        sacc = __builtin_amdgcn_mfma_f32_16x16x32_bf16(a1, b1, sacc, 0,0,0);
        for (int r = 0; r < 4; ++r) if (n <= g*4 + r) p[r] += sacc[r];
    }
    for (int off = 1; off < 16; off <<= 1)  // rowsum over the 16 j-columns
        for (int r = 0; r < 4; ++r) p[r] += __shfl_xor(p[r], off);

    if (n == 0) {
        for (int r = 0; r < 4; ++r) {
            int l = lbase + g*4 + r;
            si_[h*SEQ + l] = -p[r] * 0.125f / (ltau + (float)(l + 1));
        }
    }
}

// ---------------- K2b: per-head smax + E/P scans (R1-verbatim) ---------------
__global__ __launch_bounds__(64) void k_scan2(const float* __restrict__ G,
    const float* __restrict__ si_, float* __restrict__ es_,
    float* __restrict__ al_, float* __restrict__ be_, float* __restrict__ ga_)
{
    int h = blockIdx.x, lane = threadIdx.x;
    const float* si = si_ + h*SEQ;
    int base = lane * 16;
    float sv[16], ev[16];
    float vm = -1e30f;
#pragma unroll
    for (int i = 0; i < 16; ++i) { sv[i] = si[base + i]; vm = fmaxf(vm, sv[i]); }
    for (int off = 1; off < 64; off <<= 1) vm = fmaxf(vm, __shfl_xor(vm, off));
    float se = 0.f, ss = 0.f;
#pragma unroll
    for (int i = 0; i < 16; ++i) {
        ev[i] = expf(fminf(sv[i] - vm, 0.f));
        se += ev[i]; ss += sv[i];
    }
    float pe = se, ps = ss;
    for (int off = 1; off < 64; off <<= 1) {
        float t1 = __shfl_up(pe, off), t2 = __shfl_up(ps, off);
        if (lane >= off) { pe += t1; ps += t2; }
    }
    float E = pe - se, P = ps - ss;        // exclusive prefixes
#pragma unroll
    for (int i = 0; i < 16; ++i) {
        int l = base + i;
        E += ev[i]; P += sv[i];
        float t = (float)(l + 1);
        float s1 = 1.f / (1.f + expf(-G[(size_t)l*36 + h*3 + 0]));
        float sh = 1.f / (1.f + expf(-G[(size_t)l*36 + h*3 + 1]));
        float a = sh / (E + 1e-12f);
        float b = (s1 - sh) / t;
        float gm = -((b * P + sh) / t);
        es_[h*SEQ + l] = ev[i];
        al_[h*SEQ + l] = a;
        be_[h*SEQ + l] = b;
        ga_[h*SEQ + l] = gm;
    }
}

// ---------------- K4: causal weighted linear attention + LayerNorm -------------
__global__ __launch_bounds__(256) void k_attn(const __hip_bfloat16* __restrict__ Qb,
    const __hip_bfloat16* __restrict__ Kb, const __hip_bfloat16* __restrict__ Vt,
    const float* __restrict__ si_, const float* __restrict__ es_,
    const float* __restrict__ al_, const float* __restrict__ be_,
    const float* __restrict__ ga_, __hip_bfloat16* __restrict__ opre)
{
    int t = blockIdx.x, h = blockIdx.y;   // q-tile 0..63
    int wv = threadIdx.x >> 6, lane = threadIdx.x & 63;
    int g = lane >> 4, n = lane & 15;
    __shared__ short P[4][16*64];
    __shared__ float Op[4][16][64];
    short* Pw = P[wv];
    int m0 = t*16;
    const short* qrow = (const short*)Qb + ((size_t)h*SEQ + m0 + n)*HD + g*8;
    bf16x8 qa0 = *(const bf16x8*)qrow;
    bf16x8 qa1 = *(const bf16x8*)(qrow + 32);
    const float* al = al_ + h*SEQ;
    const float* be = be_ + h*SEQ;
    const float* ga = ga_ + h*SEQ;
    const float* es = es_ + h*SEQ;
    const float* si = si_ + h*SEQ;
    float A_[4], B_[4], G_[4];
    for (int r = 0; r < 4; ++r) {
        int m = m0 + g*4 + r;
        A_[r] = al[m]; B_[r] = be[m]; G_[r] = ga[m];
    }
    f32x4 acco[4];
    for (int et = 0; et < 4; ++et) acco[et] = (f32x4){0.f,0.f,0.f,0.f};

    int jtmax = t >> 2;
    for (int jt = wv; jt <= jtmax; jt += 4) {
        int j0 = jt*64;
        for (int ct = 0; ct < 4; ++ct) {
            const short* krow = (const short*)Kb + ((size_t)h*SEQ + j0 + ct*16 + n)*HD + g*8;
            bf16x8 kb0 = *(const bf16x8*)krow;
            bf16x8 kb1 = *(const bf16x8*)(krow + 32);
            f32x4 sacc = {0.f,0.f,0.f,0.f};
            sacc = __builtin_amdgcn_mfma_f32_16x16x32_bf16(qa0, kb0, sacc, 0, 0, 0);
            sacc = __builtin_amdgcn_mfma_f32_16x16x32_bf16(qa1, kb1, sacc, 0, 0, 0);
            int j = j0 + ct*16 + n;
            float ej = es[j], sj = si[j];
            int chunk = ct*2 + (n>>3), e = n&7;
            for (int r = 0; r < 4; ++r) {
                int m = m0 + g*4 + r;
                float w = (j <= m) ? (A_[r]*ej + B_[r]*sj + G_[r]) : 0.f;
                int ml = g*4 + r;
                Pw[ml*64 + (chunk ^ (ml&7))*8 + e] = f2bs(w * sacc[r]);
            }
        }
        const short* vb = (const short*)Vt + (size_t)h*HD*SEQ;
        for (int et = 0; et < 4; ++et) {
            for (int sub = 0; sub < 2; ++sub) {
                int q = sub*4 + g;
                bf16x8 pa = *(const bf16x8*)(&Pw[n*64 + (q ^ (n&7))*8]);
                bf16x8 vfr = *(const bf16x8*)(vb + (size_t)(et*16 + n)*SEQ + j0 + sub*32 + g*8);
                acco[et] = __builtin_amdgcn_mfma_f32_16x16x32_bf16(pa, vfr, acco[et], 0, 0, 0);
            }
        }
    }
    for (int et = 0; et < 4; ++et)
        for (int r = 0; r < 4; ++r)
            Op[wv][g*4 + r][et*16 + n] = acco[et][r];
    __syncthreads();
    for (int rr = 0; rr < 4; ++rr) {
        int row = wv*4 + rr;
        float v = Op[0][row][lane] + Op[1][row][lane] + Op[2][row][lane] + Op[3][row][lane];
        float sm = wave_reduce_sum(v);
        float sq = wave_reduce_sum(v*v);
        float mu = sm * (1.f/64.f);
        float var = fmaxf(sq * (1.f/64.f) - mu*mu, 0.f);
        float invs = rsqrtf(var + 1e-5f);
        opre[(size_t)(m0 + row)*DIM + h*HD + lane] = __float2bfloat16((v - mu) * invs);
    }
}

// ---------------- K5: output projection, A via DMA, B reg-staged from f32 Wo -
__global__ __launch_bounds__(256, 4) void k_oproj(const short* __restrict__ A,
    const float* __restrict__ Wo, float* __restrict__ out)
{
    int rt = blockIdx.x, ct = blockIdx.y;
    __shared__ short lds[16384];   // A dbuf @0/4096, B dbuf @8192/12288 (64x64)

    int tid = threadIdx.x;
    int wv = tid>>6, lane = tid&63, g = lane>>4, n = lane&15;
    int wm = wv>>1, wn = wv&1;

    float4 rb[2][2];
    auto dmaA = [&](int buf, int k0) {
        short* Ab = lds + buf*4096;
#pragma unroll
        for (int p = 0; p < 2; ++p) {
            int sbase = p*256 + wv*64;
            int s = sbase + lane;
            int r = s >> 3, c = s & 7, cl = c ^ (r & 7);
            async_copy16(A + (size_t)(rt*64 + r)*DIM + k0 + cl*8, Ab + sbase*8, lane);
        }
    };
    auto loadB = [&](int k0) {
#pragma unroll
        for (int p = 0; p < 2; ++p) {
            int s = p*256 + wv*64 + lane;
            int r = s >> 3, c = s & 7, cl = c ^ (r & 7);
            const float* sp = Wo + (size_t)(ct*64 + r)*DIM + k0 + cl*8;
            rb[p][0] = *(const float4*)sp; rb[p][1] = *(const float4*)(sp + 4);
        }
    };
    auto writeB = [&](int buf) {
        short* Bb = lds + 8192 + buf*4096;
#pragma unroll
        for (int p = 0; p < 2; ++p) {
            int s = p*256 + wv*64 + lane;
            *(bf16x8*)(Bb + s*8) = cvt8r(rb[p][0], rb[p][1]);
        }
    };

    f32x4 acc[2][2];
    for (int i=0;i<2;++i) for (int j=0;j<2;++j) acc[i][j] = (f32x4){0,0,0,0};

    dmaA(0, 0); loadB(0); writeB(0);
    for (int it = 0; it < 12; ++it) {
        __syncthreads();                      // drains A-DMA + orders B writes
        if (it < 11) { dmaA(1 - (it & 1), (it + 1)*64); loadB((it + 1)*64); }
        int buf = it & 1;
        const short* Ab = lds + buf*4096;
        const short* Bb = lds + 8192 + buf*4096;
        for (int ks = 0; ks < 2; ++ks) {
            int q = ks*4 + g;
            bf16x8 af[2], bfr[2];
            for (int i=0;i<2;++i)
                af[i] = *(const bf16x8*)(&Ab[((wm*32+i*16+n)*8 + (q ^ (n&7)))*8]);
            for (int j=0;j<2;++j)
                bfr[j] = *(const bf16x8*)(&Bb[((wn*32+j*16+n)*8 + (q ^ (n&7)))*8]);
            for (int i=0;i<2;++i)
                for (int j=0;j<2;++j)
                    acc[i][j] = __builtin_amdgcn_mfma_f32_16x16x32_bf16(af[i], bfr[j], acc[i][j], 0,0,0);
        }
        if (it < 11) writeB(1 - (it & 1));    // cvt+write after MFMA (T14)
    }
    for (int i=0;i<2;++i) for (int j=0;j<2;++j) for (int r=0;r<4;++r) {
        int row = rt*64 + wm*32 + i*16 + g*4 + r;
        int col = ct*64 + wn*32 + j*16 + n;
        out[(size_t)row*DIM + col] = acc[i][j][r];
    }
}

extern "C" void kernel_launch(void* const* d_in, const int* in_sizes, int n_in,
                              void* d_out, int out_size, void* d_ws, size_t ws_size,
                              hipStream_t stream) {
    const float* X   = (const float*)d_in[0];
    const float* Wq  = (const float*)d_in[1];
    const float* Wk  = (const float*)d_in[2];
    const float* Wv  = (const float*)d_in[3];
    const float* Wu  = (const float*)d_in[4];
    const float* Wg  = (const float*)d_in[5];
    const float* Wo  = (const float*)d_in[6];
    const float* pmu = (const float*)d_in[7];
    const float* plt = (const float*)d_in[8];

    char* w = (char*)d_ws;
    __hip_bfloat16* Qb   = (__hip_bfloat16*)(w + 0);
    __hip_bfloat16* Kb   = (__hip_bfloat16*)(w + 1572864);
    __hip_bfloat16* Vt   = (__hip_bfloat16*)(w + 3145728);
    __hip_bfloat16* opre = (__hip_bfloat16*)(w + 4718592);
    float*          G    = (float*)(w + 6291456);
    float*          si_  = (float*)(w + 6438912);
    float*          es_  = si_ + NH*SEQ;
    float*          al_  = es_ + NH*SEQ;
    float*          be_  = al_ + NH*SEQ;
    float*          ga_  = be_ + NH*SEQ;
    __hip_bfloat16* Ub   = (__hip_bfloat16*)d_out;   // scratch; k_oproj overwrites last
    float*          out  = (float*)d_out;

    hipLaunchKernelGGL(k_proj5, dim3(400), dim3(256), 0, stream,
                       X, Wq, Wk, Wv, Wu, Wg, Qb, Kb, Vt, Ub, G);
    hipLaunchKernelGGL(k_si, dim3(16, NH), dim3(256), 0, stream,
                       Ub, pmu, plt, si_);
    hipLaunchKernelGGL(k_scan2, dim3(NH), dim3(64), 0, stream,
                       G, si_, es_, al_, be_, ga_);
    hipLaunchKernelGGL(k_attn, dim3(64, NH), dim3(256), 0, stream,
                       Qb, Kb, Vt, si_, es_, al_, be_, ga_, opre);
    hipLaunchKernelGGL(k_oproj, dim3(16, 12), dim3(256), 0, stream,
                       (const short*)opre, Wo, out);
}